// Round 2
// baseline (153.743 us; speedup 1.0000x reference)
//
#include <hip/hip_runtime.h>

// Problem constants
#define BATCH  4
#define SEQL   2048
#define DMODEL 1024
#define NST    16
#define CT     64            // chunk length
#define NCH    (SEQL / CT)   // 32 chunks

// ws layout (float offsets). ws_size = 256 MiB (harness fill evidence), we use 16.8 MiB.
#define WS_P     0           // P[sigma][m]   = (A^(CT-1-sigma) B)[m]     : CT*16
#define WS_W     1024        // W[tau][m]     = (B^T A^(tau+1))[m]        : CT*16
#define WS_KV    2048        // kvext[127], kvext[63+d] = B^T A^d B, 0 for d<0
#define WS_APOW  2176        // Apow[m][k]    = (A^CT)[m][k]              : 256
#define WS_HIN   4096        // hin[b][j][d][m] = s_{j-1}                 : B*NCH*D*16
#define WS_CBUF  (WS_HIN + BATCH * NCH * DMODEL * 16)   // c[b][j][d][m]  : B*NCH*D*16

// ---------------------------------------------------------------------------
// Setup: block delta (0..64) computes A^delta in fp64 via binary powering,
// then emits its slice of the tables. (unchanged, proven)
// ---------------------------------------------------------------------------
__global__ __launch_bounds__(256) void setup_tables(const float* __restrict__ A,
                                                    const float* __restrict__ Bv,
                                                    float* __restrict__ ws) {
    __shared__ double buf0[256], buf1[256], buf2[256], buf3[256];
    __shared__ double bd[16], vtmp[16];
    double* S  = buf0;
    double* R  = buf1;
    double* Ta = buf2;
    double* Tb = buf3;
    const int t  = threadIdx.x;
    const int i  = t >> 4;
    const int kk = t & 15;
    const int delta = blockIdx.x;   // 0..64

    S[t] = (double)A[t];
    R[t] = (i == kk) ? 1.0 : 0.0;
    if (t < 16) bd[t] = (double)Bv[t];
    __syncthreads();

    for (int sb = 0; sb < 7; ++sb) {
        if ((delta >> sb) & 1) {
            double acc = 0.0;
            #pragma unroll
            for (int l = 0; l < 16; ++l) acc += R[i * 16 + l] * S[l * 16 + kk];
            Ta[t] = acc;
            __syncthreads();
            double* tmp = R; R = Ta; Ta = tmp;
        }
        if (sb < 6) {
            double acc = 0.0;
            #pragma unroll
            for (int l = 0; l < 16; ++l) acc += S[i * 16 + l] * S[l * 16 + kk];
            Tb[t] = acc;
            __syncthreads();
            double* tmp = S; S = Tb; Tb = tmp;
        }
    }
    // R now holds A^delta (fp64)

    if (delta < CT) {
        if (t < 16) {   // m = t : P[CT-1-delta][m] = (A^delta B)[m]
            double acc = 0.0;
            #pragma unroll
            for (int k = 0; k < 16; ++k) acc += R[t * 16 + k] * bd[k];
            ws[WS_P + (CT - 1 - delta) * 16 + t] = (float)acc;
            vtmp[t] = acc;
        }
        __syncthreads();
        if (t == 0) {   // k_delta = B^T A^delta B
            double kd = 0.0;
            for (int m = 0; m < 16; ++m) kd += bd[m] * vtmp[m];
            ws[WS_KV + 63 + delta] = (float)kd;
        }
    }
    if (delta >= 1 && t < 16) {   // W[delta-1][m] = sum_n B[n] (A^delta)[n][m]
        double acc = 0.0;
        #pragma unroll
        for (int n = 0; n < 16; ++n) acc += bd[n] * R[n * 16 + t];
        ws[WS_W + (delta - 1) * 16 + t] = (float)acc;
    }
    if (delta == CT) ws[WS_APOW + t] = (float)R[t];   // A^CT carry matrix
    if (delta == 0 && t < 63) ws[WS_KV + t] = 0.0f;   // zero-pad negative lags
}

// ---------------------------------------------------------------------------
// K1: full chunk state, 512 blocks. (proven body; cbuf now lives in ws)
// c_j[m] = sum_{sigma} P[sigma][m] x[sigma]
// ---------------------------------------------------------------------------
__global__ __launch_bounds__(256) void k1_chunkstate(const float* __restrict__ x,
                                                     float* __restrict__ ws) {
    const int blk  = blockIdx.x;          // 512 blocks
    const int b    = blk >> 7;
    const int j    = (blk >> 2) & 31;
    const int dblk = blk & 3;
    const int d    = dblk * 256 + threadIdx.x;

    const float* P  = ws + WS_P;          // wave-uniform -> s_load
    const float* xp = x + ((size_t)(b * SEQL + j * CT)) * DMODEL + d;

    float c[16];
    #pragma unroll
    for (int m = 0; m < 16; ++m) c[m] = 0.0f;

    float xa[8], xb[8];
    #pragma unroll
    for (int s = 0; s < 8; ++s) xa[s] = xp[(size_t)s * DMODEL];

    #pragma unroll
    for (int g = 0; g < 8; ++g) {         // 8 batches of 8 sigma
        float* cur = (g & 1) ? xb : xa;
        float* nxt = (g & 1) ? xa : xb;
        if (g < 7) {
            #pragma unroll
            for (int s = 0; s < 8; ++s)
                nxt[s] = xp[(size_t)((g + 1) * 8 + s) * DMODEL];
        }
        #pragma unroll
        for (int s = 0; s < 8; ++s) {
            const int ss = g * 8 + s;
            #pragma unroll
            for (int m = 0; m < 16; ++m)
                c[m] = fmaf(P[ss * 16 + m], cur[s], c[m]);
        }
    }

    float4* outp = (float4*)(ws + WS_CBUF + (((size_t)(b * NCH + j) * DMODEL) + d) * 16);
    #pragma unroll
    for (int q = 0; q < 4; ++q)
        outp[q] = make_float4(c[4 * q], c[4 * q + 1], c[4 * q + 2], c[4 * q + 3]);
}

// ---------------------------------------------------------------------------
// K2: carry scan over chunks. Thread = (channel d, state component m).
// (proven body; cbuf read from ws)
// s_j = Apow*s_{j-1} + c_j ; hin_j = s_{j-1}.
// ---------------------------------------------------------------------------
__global__ __launch_bounds__(256) void k2_carry(float* __restrict__ ws) {
    const int blk = blockIdx.x;           // 256 blocks
    const int b   = blk >> 6;
    const int d0  = (blk & 63) * 16;
    const int t   = threadIdx.x;
    const int m   = t & 15;
    const int ch  = t >> 4;
    const int d   = d0 + ch;
    const int laneBase = t & 48;          // 16-lane group base within wave

    const float* cbuf   = ws + WS_CBUF;
    const size_t base0   = (((size_t)(b * NCH) * DMODEL) + d) * 16 + m;
    const size_t jstride = (size_t)DMODEL * 16;

    float cpre[NCH];                      // prefetch all 32 partials upfront
    #pragma unroll
    for (int j = 0; j < NCH; ++j)
        cpre[j] = cbuf[base0 + (size_t)j * jstride];

    float Arow[16];
    #pragma unroll
    for (int k = 0; k < 16; ++k) Arow[k] = ws[WS_APOW + m * 16 + k];

    float* hin = ws + WS_HIN;
    float s = 0.0f;
    #pragma unroll
    for (int j = 0; j < NCH; ++j) {
        hin[base0 + (size_t)j * jstride] = s;
        float acc = cpre[j];
        #pragma unroll
        for (int k = 0; k < 16; ++k)
            acc = fmaf(Arow[k], __shfl(s, laneBase + k, 64), acc);
        s = acc;
    }
}

// ---------------------------------------------------------------------------
// K3-new: 512 blocks, each = (b, chunk j, 256-channel slice). The 64x256
// x-tile is staged into LDS ONCE (64 KiB -> 2 blocks/CU) and ALL 64 taus are
// computed from it: x read 1x (was 2.5x), h_in read 1x (was 4x).
//   y[tau] = W[tau].h_in + sum_{s<=tau} kv[tau-s] x[s]
// Triangle = 2080 statically-unrolled FMAs/thread; xs reads are stride-1
// across lanes (2 lanes/bank = free); kv/W are wave-uniform (s_loads).
// ---------------------------------------------------------------------------
__global__ __launch_bounds__(256, 2) void k3_output(const float* __restrict__ x,
                                                    const float* __restrict__ ws,
                                                    float* __restrict__ y) {
    __shared__ __align__(16) float xs[CT * 256];   // [sigma][d_local], 64 KiB
    const int blk  = blockIdx.x;          // 512 blocks
    const int b    = blk >> 7;
    const int j    = (blk >> 2) & 31;
    const int dblk = blk & 3;
    const int t    = threadIdx.x;
    const int d    = dblk * 256 + t;

    // stage x tile (float4; wave reads 1 KiB contiguous per row)
    {
        const float* xp = x + ((size_t)(b * SEQL + j * CT)) * DMODEL + dblk * 256;
        const int wave = t >> 6, lane = t & 63;
        #pragma unroll
        for (int r = 0; r < 16; ++r) {
            const int sigma = wave * 16 + r;        // 4 waves x 16 rows = 64 rows
            *(float4*)(&xs[sigma * 256 + lane * 4]) =
                *(const float4*)(xp + (size_t)sigma * DMODEL + lane * 4);
        }
    }

    // h_in load overlaps the LDS stage (no dependence on xs)
    const float* hinp = ws + WS_HIN + (((size_t)(b * NCH + j) * DMODEL) + d) * 16;
    float4 hv[4];
    #pragma unroll
    for (int q = 0; q < 4; ++q) hv[q] = ((const float4*)hinp)[q];

    float h[16];
    #pragma unroll
    for (int q = 0; q < 4; ++q) {
        h[4 * q]     = hv[q].x; h[4 * q + 1] = hv[q].y;
        h[4 * q + 2] = hv[q].z; h[4 * q + 3] = hv[q].w;
    }

    // correction term first (matches proven numerics): yv[tau] = W[tau].h_in
    const float* W = ws + WS_W;
    float yv[CT];
    #pragma unroll
    for (int tau = 0; tau < CT; ++tau) {
        float acc = 0.0f;
        #pragma unroll
        for (int m = 0; m < 16; ++m) acc = fmaf(W[tau * 16 + m], h[m], acc);
        yv[tau] = acc;
    }

    __syncthreads();

    // causal triangle from the resident LDS tile: 64 LDS reads, 2080 FMAs
    const float* kv63 = ws + WS_KV + 63;  // kv63[q] = B^T A^q B, q in [0,63]
    #pragma unroll
    for (int ss = 0; ss < CT; ++ss) {
        const float xv = xs[ss * 256 + t];
        #pragma unroll
        for (int q = 0; q < CT - ss; ++q)          // tau = ss + q
            yv[ss + q] = fmaf(kv63[q], xv, yv[ss + q]);
    }

    float* yp = y + ((size_t)(b * SEQL + j * CT)) * DMODEL + d;
    #pragma unroll
    for (int tau = 0; tau < CT; ++tau) yp[(size_t)tau * DMODEL] = yv[tau];
}

// ---------------------------------------------------------------------------
extern "C" void kernel_launch(void* const* d_in, const int* in_sizes, int n_in,
                              void* d_out, int out_size, void* d_ws, size_t ws_size,
                              hipStream_t stream) {
    (void)in_sizes; (void)n_in; (void)out_size; (void)ws_size;
    const float* x  = (const float*)d_in[0];
    const float* A  = (const float*)d_in[1];
    const float* Bv = (const float*)d_in[2];
    float* out = (float*)d_out;
    float* ws  = (float*)d_ws;

    setup_tables<<<65, 256, 0, stream>>>(A, Bv, ws);
    k1_chunkstate<<<512, 256, 0, stream>>>(x, ws);
    k2_carry<<<256, 256, 0, stream>>>(ws);
    k3_output<<<512, 256, 0, stream>>>(x, ws, out);
}

// Round 3
// 123.226 us; speedup vs baseline: 1.2477x; 1.2477x over previous
//
#include <hip/hip_runtime.h>

// Problem constants
#define BATCH  4
#define SEQL   2048
#define DMODEL 1024
#define NST    16
#define CT     64            // chunk length
#define NCH    (SEQL / CT)   // 32 chunks

// ws layout (float offsets). ws_size = 256 MiB, we use ~16.8 MiB.
#define WS_P     0           // P[sigma][m]   = (A^(CT-1-sigma) B)[m]     : CT*16
#define WS_W     1024        // W[tau][m]     = (B^T A^(tau+1))[m]        : CT*16
#define WS_KV    2048        // kvext[127], kvext[63+d] = B^T A^d B, 0 for d<0
#define WS_APOW  2176        // Apow[m][k]    = (A^CT)[m][k]              : 256
#define WS_HIN   4096        // hin[b][j][d][m] = s_{j-1}                 : B*NCH*D*16
#define WS_CBUF  (WS_HIN + BATCH * NCH * DMODEL * 16)   // c[b][j][d][m]  : B*NCH*D*16

// ---------------------------------------------------------------------------
// Setup: block delta (0..64) computes A^delta in fp64 via binary powering,
// then emits its slice of the tables. (unchanged, proven)
// ---------------------------------------------------------------------------
__global__ __launch_bounds__(256) void setup_tables(const float* __restrict__ A,
                                                    const float* __restrict__ Bv,
                                                    float* __restrict__ ws) {
    __shared__ double buf0[256], buf1[256], buf2[256], buf3[256];
    __shared__ double bd[16], vtmp[16];
    double* S  = buf0;
    double* R  = buf1;
    double* Ta = buf2;
    double* Tb = buf3;
    const int t  = threadIdx.x;
    const int i  = t >> 4;
    const int kk = t & 15;
    const int delta = blockIdx.x;   // 0..64

    S[t] = (double)A[t];
    R[t] = (i == kk) ? 1.0 : 0.0;
    if (t < 16) bd[t] = (double)Bv[t];
    __syncthreads();

    for (int sb = 0; sb < 7; ++sb) {
        if ((delta >> sb) & 1) {
            double acc = 0.0;
            #pragma unroll
            for (int l = 0; l < 16; ++l) acc += R[i * 16 + l] * S[l * 16 + kk];
            Ta[t] = acc;
            __syncthreads();
            double* tmp = R; R = Ta; Ta = tmp;
        }
        if (sb < 6) {
            double acc = 0.0;
            #pragma unroll
            for (int l = 0; l < 16; ++l) acc += S[i * 16 + l] * S[l * 16 + kk];
            Tb[t] = acc;
            __syncthreads();
            double* tmp = S; S = Tb; Tb = tmp;
        }
    }
    // R now holds A^delta (fp64)

    if (delta < CT) {
        if (t < 16) {   // m = t : P[CT-1-delta][m] = (A^delta B)[m]
            double acc = 0.0;
            #pragma unroll
            for (int k = 0; k < 16; ++k) acc += R[t * 16 + k] * bd[k];
            ws[WS_P + (CT - 1 - delta) * 16 + t] = (float)acc;
            vtmp[t] = acc;
        }
        __syncthreads();
        if (t == 0) {   // k_delta = B^T A^delta B
            double kd = 0.0;
            for (int m = 0; m < 16; ++m) kd += bd[m] * vtmp[m];
            ws[WS_KV + 63 + delta] = (float)kd;
        }
    }
    if (delta >= 1 && t < 16) {   // W[delta-1][m] = sum_n B[n] (A^delta)[n][m]
        double acc = 0.0;
        #pragma unroll
        for (int n = 0; n < 16; ++n) acc += bd[n] * R[n * 16 + t];
        ws[WS_W + (delta - 1) * 16 + t] = (float)acc;
    }
    if (delta == CT) ws[WS_APOW + t] = (float)R[t];   // A^CT carry matrix
    if (delta == 0 && t < 63) ws[WS_KV + t] = 0.0f;   // zero-pad negative lags
}

// ---------------------------------------------------------------------------
// K1: full chunk state, 512 blocks. (unchanged from proven baseline)
// c_j[m] = sum_{sigma} P[sigma][m] x[sigma]
// ---------------------------------------------------------------------------
__global__ __launch_bounds__(256) void k1_chunkstate(const float* __restrict__ x,
                                                     float* __restrict__ ws) {
    const int blk  = blockIdx.x;          // 512 blocks
    const int b    = blk >> 7;
    const int j    = (blk >> 2) & 31;
    const int dblk = blk & 3;
    const int d    = dblk * 256 + threadIdx.x;

    const float* P  = ws + WS_P;          // wave-uniform -> s_load
    const float* xp = x + ((size_t)(b * SEQL + j * CT)) * DMODEL + d;

    float c[16];
    #pragma unroll
    for (int m = 0; m < 16; ++m) c[m] = 0.0f;

    float xa[8], xb[8];
    #pragma unroll
    for (int s = 0; s < 8; ++s) xa[s] = xp[(size_t)s * DMODEL];

    #pragma unroll
    for (int g = 0; g < 8; ++g) {         // 8 batches of 8 sigma
        float* cur = (g & 1) ? xb : xa;
        float* nxt = (g & 1) ? xa : xb;
        if (g < 7) {
            #pragma unroll
            for (int s = 0; s < 8; ++s)
                nxt[s] = xp[(size_t)((g + 1) * 8 + s) * DMODEL];
        }
        #pragma unroll
        for (int s = 0; s < 8; ++s) {
            const int ss = g * 8 + s;
            #pragma unroll
            for (int m = 0; m < 16; ++m)
                c[m] = fmaf(P[ss * 16 + m], cur[s], c[m]);
        }
    }

    float4* outp = (float4*)(ws + WS_CBUF + (((size_t)(b * NCH + j) * DMODEL) + d) * 16);
    #pragma unroll
    for (int q = 0; q < 4; ++q)
        outp[q] = make_float4(c[4 * q], c[4 * q + 1], c[4 * q + 2], c[4 * q + 3]);
}

// ---------------------------------------------------------------------------
// K2: carry scan over chunks. (unchanged from proven baseline)
// s_j = Apow*s_{j-1} + c_j ; hin_j = s_{j-1}.
// ---------------------------------------------------------------------------
__global__ __launch_bounds__(256) void k2_carry(float* __restrict__ ws) {
    const int blk = blockIdx.x;           // 256 blocks
    const int b   = blk >> 6;
    const int d0  = (blk & 63) * 16;
    const int t   = threadIdx.x;
    const int m   = t & 15;
    const int ch  = t >> 4;
    const int d   = d0 + ch;
    const int laneBase = t & 48;          // 16-lane group base within wave

    const float* cbuf   = ws + WS_CBUF;
    const size_t base0   = (((size_t)(b * NCH) * DMODEL) + d) * 16 + m;
    const size_t jstride = (size_t)DMODEL * 16;

    float cpre[NCH];                      // prefetch all 32 partials upfront
    #pragma unroll
    for (int j = 0; j < NCH; ++j)
        cpre[j] = cbuf[base0 + (size_t)j * jstride];

    float Arow[16];
    #pragma unroll
    for (int k = 0; k < 16; ++k) Arow[k] = ws[WS_APOW + m * 16 + k];

    float* hin = ws + WS_HIN;
    float s = 0.0f;
    #pragma unroll
    for (int j = 0; j < NCH; ++j) {
        hin[base0 + (size_t)j * jstride] = s;
        float acc = cpre[j];
        #pragma unroll
        for (int k = 0; k < 16; ++k)
            acc = fmaf(Arow[k], __shfl(s, laneBase + k, 64), acc);
        s = acc;
    }
}

// ---------------------------------------------------------------------------
// K3 v3: 2048 blocks (8/CU), block = (b, chunk j, 64-channel slice).
// LDS tile = 64 sigma x 64 ch = 16 KiB -> 8 blocks/CU -> up to 32 waves/CU.
// Thread = (tau-quarter tq = wave, channel dl). Each thread: 16 taus.
//   y[tau] = W[tau].h_in + sum_{s<=tau} kv[tau-s] x[s]
// x read once per tile (32 MB total), triangle fed from LDS (stride-1 lanes,
// 2-way bank alias = free), kv/W wave-uniform (s_loads). Triangle depth is
// wave-uniform -> template dispatch, fully static unroll.
// ---------------------------------------------------------------------------
template <int TT>
__device__ __forceinline__ void k3_body(const float* __restrict__ xs,
                                        const float* __restrict__ ws,
                                        float* __restrict__ y,
                                        int b, int j, int d, int dl) {
    // h_in loads issue first; stage/compute overlap their latency
    const float* hinp = ws + WS_HIN + (((size_t)(b * NCH + j) * DMODEL) + d) * 16;
    float4 hv[4];
    #pragma unroll
    for (int q = 0; q < 4; ++q) hv[q] = ((const float4*)hinp)[q];

    float h[16];
    #pragma unroll
    for (int q = 0; q < 4; ++q) {
        h[4 * q]     = hv[q].x; h[4 * q + 1] = hv[q].y;
        h[4 * q + 2] = hv[q].z; h[4 * q + 3] = hv[q].w;
    }

    // correction term: yv[i] = W[TT*16+i] . h_in
    const float* W = ws + WS_W + TT * 16 * 16;
    float yv[16];
    #pragma unroll
    for (int i = 0; i < 16; ++i) {
        float acc = 0.0f;
        #pragma unroll
        for (int m = 0; m < 16; ++m) acc = fmaf(W[i * 16 + m], h[m], acc);
        yv[i] = acc;
    }

    __syncthreads();                      // xs tile ready

    // causal triangle from LDS: static bounds, wave-uniform kv scalars
    const float* kv63 = ws + WS_KV + 63;  // kv63[q] = B^T A^q B, q in [0,63]
    #pragma unroll
    for (int ss = 0; ss < (TT + 1) * 16; ++ss) {
        const float xv = xs[ss * 64 + dl];
        #pragma unroll
        for (int i = 0; i < 16; ++i) {
            if (TT * 16 + i >= ss)        // compile-time per (ss,i)
                yv[i] = fmaf(kv63[TT * 16 + i - ss], xv, yv[i]);
        }
    }

    float* yp = y + ((size_t)(b * SEQL + j * CT + TT * 16)) * DMODEL + d;
    #pragma unroll
    for (int i = 0; i < 16; ++i) yp[(size_t)i * DMODEL] = yv[i];
}

__global__ __launch_bounds__(256, 8) void k3_output(const float* __restrict__ x,
                                                    const float* __restrict__ ws,
                                                    float* __restrict__ y) {
    __shared__ __align__(16) float xs[CT * 64];    // [sigma][dl], 16 KiB
    const int blk  = blockIdx.x;          // 2048 blocks
    const int b    = blk >> 9;
    const int j    = (blk >> 4) & 31;
    const int dblk = blk & 15;            // 16 slices of 64 channels
    const int t    = threadIdx.x;
    const int tq   = t >> 6;              // tau quarter = wave index
    const int dl   = t & 63;
    const int d    = dblk * 64 + dl;

    // stage x tile: 1024 float4s, 4 per thread (16 lanes/row -> 256B rows)
    {
        const float* xp = x + ((size_t)(b * SEQL + j * CT)) * DMODEL + dblk * 64;
        #pragma unroll
        for (int k = 0; k < 4; ++k) {
            const int f     = k * 256 + t;        // 0..1023
            const int sigma = f >> 4;
            const int c4    = f & 15;
            *(float4*)(&xs[sigma * 64 + c4 * 4]) =
                *(const float4*)(xp + (size_t)sigma * DMODEL + c4 * 4);
        }
    }
    // note: __syncthreads happens inside k3_body (after W.h overlap work)

    switch (tq) {                          // wave-uniform branch
        case 0: k3_body<0>(xs, ws, y, b, j, d, dl); break;
        case 1: k3_body<1>(xs, ws, y, b, j, d, dl); break;
        case 2: k3_body<2>(xs, ws, y, b, j, d, dl); break;
        default: k3_body<3>(xs, ws, y, b, j, d, dl); break;
    }
}

// ---------------------------------------------------------------------------
extern "C" void kernel_launch(void* const* d_in, const int* in_sizes, int n_in,
                              void* d_out, int out_size, void* d_ws, size_t ws_size,
                              hipStream_t stream) {
    (void)in_sizes; (void)n_in; (void)out_size; (void)ws_size;
    const float* x  = (const float*)d_in[0];
    const float* A  = (const float*)d_in[1];
    const float* Bv = (const float*)d_in[2];
    float* out = (float*)d_out;
    float* ws  = (float*)d_ws;

    setup_tables<<<65, 256, 0, stream>>>(A, Bv, ws);
    k1_chunkstate<<<512, 256, 0, stream>>>(x, ws);
    k2_carry<<<256, 256, 0, stream>>>(ws);
    k3_output<<<2048, 256, 0, stream>>>(x, ws, out);
}

// Round 4
// 119.138 us; speedup vs baseline: 1.2905x; 1.0343x over previous
//
#include <hip/hip_runtime.h>

// Problem constants
#define BATCH  4
#define SEQL   2048
#define DMODEL 1024
#define NST    16
#define CT     64            // chunk length
#define NCH    (SEQL / CT)   // 32 chunks

// ws layout (float offsets). ws_size = 256 MiB, we use ~8.5 MiB.
#define WS_W     1024        // W[tau][m] = (B^T A^(tau+1))[m]  : 64*16
#define WS_KV    2048        // kvext[127]; kvext[63+d] = B^T A^d B
#define WS_HIN   4096        // hin[b][j][d][m] = s_{j-1}       : B*NCH*D*16

// ---------------------------------------------------------------------------
// KA: fused tables + chunk-state + carry scan. 256 blocks x 256 threads.
// Block = (b, 16-channel group). Thread = (ch = t>>4, m = t&15).
//
// Phase T (per-block, redundant, ~1 us): fp64 log-depth doubling builds
//   v_d = A^d B (d=0..63), w_d = B^T A^d (d=0..64), Apow = A^64
//   -> Pl[sigma][m] = v_{63-sigma}[m], W/kv written to ws for K3.
// Phase S (32 chunks): stage x tile [64 sigma x 16 ch] transposed into
//   xs[16][68] (pad 68 keeps 16B alignment + 2-way banks = free);
//   c(ch,m) = sum_sigma Preg[sigma] * xs[ch][sigma] via ds_read_b128;
//   hin write (coalesced 1KB/block); scan s = Apow*s + c via 16-lane shfl.
// cbuf never exists in memory; K1's 16 MiB round trip is gone.
// ---------------------------------------------------------------------------
__global__ __launch_bounds__(256) void ka_tables_scan(const float* __restrict__ x,
                                                      const float* __restrict__ Ain,
                                                      const float* __restrict__ Bvin,
                                                      float* __restrict__ ws) {
    __shared__ double M[256], Mt[256];     // A^(2^k), scratch
    __shared__ double Vd[64][16];          // v_d = A^d B
    __shared__ double Wd[65][16];          // w_d = B^T A^d
    __shared__ double bd[16];
    __shared__ float  Pl[64][16];          // P[sigma][m] = v_{63-sigma}[m]
    __shared__ float  Ap[256];             // A^64 fp32
    __shared__ __align__(16) float xs[16][68];   // transposed x tile, padded

    const int t   = threadIdx.x;
    const int blk = blockIdx.x;            // 256 blocks
    const int b   = blk >> 6;
    const int g   = blk & 63;
    const int d0  = g * 16;

    // ---------------- Phase T: tables via fp64 doubling ----------------
    M[t] = (double)Ain[t];
    if (t < 16) {
        bd[t]    = (double)Bvin[t];
        Vd[0][t] = (double)Bvin[t];        // v_0 = B
        Wd[0][t] = (double)Bvin[t];        // w_0 = B^T
    }
    __syncthreads();

    #pragma unroll
    for (int k = 0; k < 6; ++k) {          // M = A^(2^k) entering round k
        const int cnt = 1 << k;
        const int m   = t & 15;
        // batch matvecs: d' = dd + cnt for dd in [0, cnt)
        for (int dd = t >> 4; dd < cnt; dd += 16) {
            double av = 0.0, aw = 0.0;
            #pragma unroll
            for (int l = 0; l < 16; ++l) {
                av += M[m * 16 + l] * Vd[dd][l];   // (A^{2^k} v_dd)[m]
                aw += Wd[dd][l] * M[l * 16 + m];   // (w_dd A^{2^k})[m]
            }
            Vd[dd + cnt][m] = av;
            Wd[dd + cnt][m] = aw;
        }
        __syncthreads();
        // square M (all threads); at k=5 also w_64 = w_32 * A^32
        {
            const int i = t >> 4, jj = t & 15;
            double acc = 0.0;
            #pragma unroll
            for (int l = 0; l < 16; ++l) acc += M[i * 16 + l] * M[l * 16 + jj];
            Mt[t] = acc;
            if (k == 5 && t < 16) {
                double aw = 0.0;
                #pragma unroll
                for (int l = 0; l < 16; ++l) aw += Wd[32][l] * M[l * 16 + t];
                Wd[64][t] = aw;
            }
        }
        __syncthreads();
        M[t] = Mt[t];                      // M = A^(2^{k+1})
        __syncthreads();
    }
    // M = A^64. Vd[0..63], Wd[0..64] complete.

    // fp32 tables + global writes for K3 (all blocks write identical data)
    Ap[t] = (float)M[t];
    for (int e = t; e < 1024; e += 256) {
        const int r = e >> 4, mm = e & 15;
        Pl[r][mm] = (float)Vd[63 - r][mm];            // P[sigma][m]
        ws[WS_W + e] = (float)Wd[r + 1][mm];          // W[tau][m] = w_{tau+1}
    }
    if (t < 64) {                                      // kv[d] = B^T A^d B
        double kd = 0.0;
        #pragma unroll
        for (int mm = 0; mm < 16; ++mm) kd += bd[mm] * Vd[t][mm];
        ws[WS_KV + 63 + t] = (float)kd;
    }
    __syncthreads();

    // ---------------- Phase S: chunk states + carry scan ----------------
    const int ch = t >> 4;                 // channel within group
    const int m  = t & 15;                 // state component
    const int d  = d0 + ch;
    const int laneBase = t & 48;           // 16-lane group base within wave
    const int sigt = t >> 2;               // stage role: sigma row
    const int c4   = t & 3;                // stage role: float4 column

    float Preg[64];                        // P[.][m] column in registers
    #pragma unroll
    for (int sg = 0; sg < 64; ++sg) Preg[sg] = Pl[sg][m];

    float Arow[16];
    #pragma unroll
    for (int k = 0; k < 16; ++k) Arow[k] = Ap[m * 16 + k];

    const float* xb = x + (size_t)(b * SEQL) * DMODEL + d0;
    float* hin = ws + WS_HIN;

    float4 cur = *(const float4*)(xb + (size_t)sigt * DMODEL + c4 * 4);

    float s = 0.0f;
    for (int j = 0; j < NCH; ++j) {
        __syncthreads();                   // prior compute done reading xs
        xs[c4 * 4 + 0][sigt] = cur.x;      // transposed store, 2-way banks
        xs[c4 * 4 + 1][sigt] = cur.y;
        xs[c4 * 4 + 2][sigt] = cur.z;
        xs[c4 * 4 + 3][sigt] = cur.w;
        __syncthreads();
        if (j + 1 < NCH)                   // prefetch next tile under compute
            cur = *(const float4*)(xb + (size_t)((j + 1) * CT + sigt) * DMODEL + c4 * 4);

        // c(ch,m) = sum_sigma P[sigma][m] x[sigma][ch]
        float c = 0.0f;
        #pragma unroll
        for (int sg = 0; sg < 16; ++sg) {
            const float4 xv = *(const float4*)(&xs[ch][sg * 4]);
            c = fmaf(Preg[4 * sg + 0], xv.x, c);
            c = fmaf(Preg[4 * sg + 1], xv.y, c);
            c = fmaf(Preg[4 * sg + 2], xv.z, c);
            c = fmaf(Preg[4 * sg + 3], xv.w, c);
        }

        // hin_j = s_{j-1}; addr across t is consecutive (coalesced 1 KB)
        hin[(((size_t)(b * NCH + j) * DMODEL) + d0) * 16 + t] = s;

        // s_j = Apow * s_{j-1} + c  (16-lane shfl mat-vec, proven K2 layout)
        float acc = c;
        #pragma unroll
        for (int k = 0; k < 16; ++k)
            acc = fmaf(Arow[k], __shfl(s, laneBase + k, 64), acc);
        s = acc;
    }
}

// ---------------------------------------------------------------------------
// K3: unchanged from proven round-3 version (22 us). 2048 blocks (8/CU),
// block = (b, chunk j, 64-channel slice), LDS tile 16 KiB, all 64 taus.
//   y[tau] = W[tau].h_in + sum_{s<=tau} kv[tau-s] x[s]
// ---------------------------------------------------------------------------
template <int TT>
__device__ __forceinline__ void k3_body(const float* __restrict__ xs,
                                        const float* __restrict__ ws,
                                        float* __restrict__ y,
                                        int b, int j, int d, int dl) {
    const float* hinp = ws + WS_HIN + (((size_t)(b * NCH + j) * DMODEL) + d) * 16;
    float4 hv[4];
    #pragma unroll
    for (int q = 0; q < 4; ++q) hv[q] = ((const float4*)hinp)[q];

    float h[16];
    #pragma unroll
    for (int q = 0; q < 4; ++q) {
        h[4 * q]     = hv[q].x; h[4 * q + 1] = hv[q].y;
        h[4 * q + 2] = hv[q].z; h[4 * q + 3] = hv[q].w;
    }

    const float* W = ws + WS_W + TT * 16 * 16;
    float yv[16];
    #pragma unroll
    for (int i = 0; i < 16; ++i) {
        float acc = 0.0f;
        #pragma unroll
        for (int m = 0; m < 16; ++m) acc = fmaf(W[i * 16 + m], h[m], acc);
        yv[i] = acc;
    }

    __syncthreads();                      // xs tile ready

    const float* kv63 = ws + WS_KV + 63;  // kv63[q] = B^T A^q B
    #pragma unroll
    for (int ss = 0; ss < (TT + 1) * 16; ++ss) {
        const float xv = xs[ss * 64 + dl];
        #pragma unroll
        for (int i = 0; i < 16; ++i) {
            if (TT * 16 + i >= ss)
                yv[i] = fmaf(kv63[TT * 16 + i - ss], xv, yv[i]);
        }
    }

    float* yp = y + ((size_t)(b * SEQL + j * CT + TT * 16)) * DMODEL + d;
    #pragma unroll
    for (int i = 0; i < 16; ++i) yp[(size_t)i * DMODEL] = yv[i];
}

__global__ __launch_bounds__(256, 8) void k3_output(const float* __restrict__ x,
                                                    const float* __restrict__ ws,
                                                    float* __restrict__ y) {
    __shared__ __align__(16) float xs[CT * 64];    // [sigma][dl], 16 KiB
    const int blk  = blockIdx.x;          // 2048 blocks
    const int b    = blk >> 9;
    const int j    = (blk >> 4) & 31;
    const int dblk = blk & 15;
    const int t    = threadIdx.x;
    const int tq   = t >> 6;              // tau quarter = wave index
    const int dl   = t & 63;
    const int d    = dblk * 64 + dl;

    {
        const float* xp = x + ((size_t)(b * SEQL + j * CT)) * DMODEL + dblk * 64;
        #pragma unroll
        for (int k = 0; k < 4; ++k) {
            const int f     = k * 256 + t;
            const int sigma = f >> 4;
            const int cc    = f & 15;
            *(float4*)(&xs[sigma * 64 + cc * 4]) =
                *(const float4*)(xp + (size_t)sigma * DMODEL + cc * 4);
        }
    }

    switch (tq) {                          // wave-uniform branch
        case 0: k3_body<0>(xs, ws, y, b, j, d, dl); break;
        case 1: k3_body<1>(xs, ws, y, b, j, d, dl); break;
        case 2: k3_body<2>(xs, ws, y, b, j, d, dl); break;
        default: k3_body<3>(xs, ws, y, b, j, d, dl); break;
    }
}

// ---------------------------------------------------------------------------
extern "C" void kernel_launch(void* const* d_in, const int* in_sizes, int n_in,
                              void* d_out, int out_size, void* d_ws, size_t ws_size,
                              hipStream_t stream) {
    (void)in_sizes; (void)n_in; (void)out_size; (void)ws_size;
    const float* x  = (const float*)d_in[0];
    const float* A  = (const float*)d_in[1];
    const float* Bv = (const float*)d_in[2];
    float* out = (float*)d_out;
    float* ws  = (float*)d_ws;

    ka_tables_scan<<<256, 256, 0, stream>>>(x, A, Bv, ws);
    k3_output<<<2048, 256, 0, stream>>>(x, ws, out);
}